// Round 11
// baseline (279.063 us; speedup 1.0000x reference)
//
#include <hip/hip_runtime.h>

typedef unsigned short u16;
typedef unsigned int   u32;
typedef unsigned long long u64;
typedef __attribute__((ext_vector_type(8))) short bf16x8;
typedef __attribute__((ext_vector_type(4))) float f32x4;

#define NOBS 128
#define NN   1280
#define NH   256
#define NO   80
#define TT   5
#define RR   16          // batch rows per block
#define NTHR 512         // 8 waves/block, 2 col-tiles per wave
#define BP1  88          // layer1 bits LDS pitch (u16)
#define BP2  20          // layer2/3 bits pitch (u16)

// ws layout (u16 units), 3-way bf16 split (hi | mid | lo grouped per matrix):
//   W1s [3][20][256][64] @0 ; W2s [3][4][256][64] @983040 ; Wos [3][4][128][64] @1179648
//   gbits [8192 rows][5 t][80] @1277952  (spike bit-planes, 16 bits/u16 word)
#define W1TOT   983040
#define W2S_OFF 983040
#define WOS_OFF 1179648
#define WS_TOTAL 1277952
#define GB_OFF  WS_TOTAL

#define PREP_BLOCKS 4992          // WS_TOTAL/256
#define ENC_BLOCKS  2560          // 8192*80/256 (one thread per u16 bit-word)

// scheduler hint: SCHED_GRP(mask, n) pins "n insts of class mask" into the
// next scheduling group. 0x020 = VMEM read, 0x008 = MFMA.
#define SCHED_GRP(m, n) __builtin_amdgcn_sched_group_barrier((m), (n), 0)

__device__ __forceinline__ float bf2f(u16 u) {
  union { u32 i; float f; } x; x.i = ((u32)u) << 16; return x.f;
}
__device__ __forceinline__ u16 f2bf(float f) {
  union { float f; u32 i; } x; x.f = f;
  u32 i = x.i + 0x7FFFu + ((x.i >> 16) & 1u);   // RNE
  return (u16)(i >> 16);
}

// 3-way bf16 split: w ~= hi + mid + lo, residual <= 2^-27 |w|.
__device__ __forceinline__ u16 split3(float w, int sel) {
  u16 hi = f2bf(w);
  if (sel == 0) return hi;
  float r1 = __fsub_rn(w, bf2f(hi));        // exact
  u16 mid = f2bf(r1);
  if (sel == 1) return mid;
  float r2 = __fsub_rn(r1, bf2f(mid));      // exact
  return f2bf(r2);
}

// Inline near-correctly-rounded f32 exp via f64 degree-11 Taylor.
__device__ __forceinline__ float exp_cr(float arg) {
  double xa = (double)arg;
  double nd = __builtin_rint(xa * 1.4426950408889634074);
  double r  = fma(nd, -6.93147180369123816490e-01, xa);
  r         = fma(nd, -1.90821492927058770002e-10, r);
  double p = 2.50521083854417187751e-08;
  p = fma(p, r, 2.75573192239858906526e-07);
  p = fma(p, r, 2.75573192239858906526e-06);
  p = fma(p, r, 2.48015873015873015873e-05);
  p = fma(p, r, 1.98412698412698412698e-04);
  p = fma(p, r, 1.38888888888888888889e-03);
  p = fma(p, r, 8.33333333333333333333e-03);
  p = fma(p, r, 4.16666666666666666667e-02);
  p = fma(p, r, 1.66666666666666666667e-01);
  p = fma(p, r, 0.5);
  p = fma(p, r, 1.0);
  p = fma(p, r, 1.0);
  int n = (int)nd;
  union { u64 u; double d; } s;
  s.u = ((u64)(u32)(n + 1023)) << 52;
  return (n < -150) ? 0.f : (float)(s.d * p);
}

// Fused prep: blocks [0,4992) split weights; blocks [4992,7552) run the encoder.
__global__ __launch_bounds__(256) void prep_kernel(
    const float* __restrict__ W1, const float* __restrict__ W2,
    const float* __restrict__ Wo,
    const float* __restrict__ obs, const float* __restrict__ enc_mean,
    const float* __restrict__ enc_std, u16* __restrict__ ws)
{
  int bid = blockIdx.x;
  if (bid < PREP_BLOCKS) {
    int i = bid * 256 + threadIdx.x;
    if (i < W1TOT) {                          // W1 [256][1280]
      int sel = i / 327680, rem = i - sel * 327680;
      int kc = rem >> 14, r = rem & 16383, j = r >> 6, kk = r & 63;
      ws[i] = split3(W1[j * 1280 + kc * 64 + kk], sel);
    } else if (i < WOS_OFF) {                 // W2 [256][256]
      int i2 = i - W2S_OFF;
      int sel = i2 >> 16, rem = i2 & 65535;
      int kc = rem >> 14, j = (rem >> 6) & 255, kk = rem & 63;
      ws[i] = split3(W2[j * 256 + kc * 64 + kk], sel);
    } else {                                  // Wo [80][256] padded to 128 rows
      int i3 = i - WOS_OFF;
      int sel = i3 >> 15, rem = i3 & 32767;
      int kc = rem >> 13, j = (rem >> 6) & 127, kk = rem & 63;
      float w = (j < NO) ? Wo[j * 256 + kc * 64 + kk] : 0.f;
      ws[i] = split3(w, sel);
    }
    return;
  }
  // ---- encoder ----
  int gid = (bid - PREP_BLOCKS) * 256 + threadIdx.x;   // < 8192*80
  int r = gid / 80, w = gid - (gid / 80) * 80;
  const float* obsrow = obs + r * NOBS;
  u32 wbits[TT] = {0, 0, 0, 0, 0};
  #pragma unroll
  for (int e = 0; e < 16; ++e) {
    int k = w * 16 + e;
    int f = k / 10;
    float x  = obsrow[f];
    float m  = enc_mean[k];
    float sd = enc_std[k];
    float d  = __fsub_rn(x, m);
    float arg = __fdiv_rn(__fmul_rn(-0.5f, __fmul_rn(d, d)), __fmul_rn(sd, sd));
    float a = exp_cr(arg);
    float v = 0.f;
    #pragma unroll
    for (int t = 0; t < TT; ++t) {
      v = __fadd_rn(v, a);
      if (v > 0.999f) { wbits[t] |= (1u << e); v = __fsub_rn(v, 0.999f); }
    }
  }
  u16* gb = ws + GB_OFF + r * 400 + w;       // [row][t][80]
  #pragma unroll
  for (int t = 0; t < TT; ++t) gb[t * 80] = (u16)wbits[t];
}

// Expand 8 spike bits (one byte) -> bf16x8 A-fragment; mul-spread, 4 VALU/u32.
__device__ __forceinline__ void build_afr(bf16x8 afr[TT], const u64 bw[TT], int sh) {
  #pragma unroll
  for (int t = 0; t < TT; ++t) {
    u32 b = (u32)(bw[t] >> sh) & 0xFFu;
    union { u32 u[4]; bf16x8 v; } x;
    #pragma unroll
    for (int i = 0; i < 4; ++i) {
      u32 two = (b >> (2 * i)) & 3u;
      x.u[i] = ((two * 0x8001u) & 0x00010001u) * 0x3F80u;
    }
    afr[t] = x.v;
  }
}

// Barrier-free merged-split GEMM, 2 col-tiles/wave, single merged accumulator.
// Depth-3 B pipeline (circular queue, slot = G % 3); sched_group_barrier pins
// the (2 VMEM -> 10 MFMA) interleave per sel-group so the register allocator /
// scheduler cannot sink the queue loads to their uses.
__device__ __forceinline__ void gemm2(
    const u16* __restrict__ lbits, int bpitch,
    const u16* __restrict__ wsbase, int selstride, int nkc, int nrowB,
    int wv, int lane, f32x4 acc[2][TT])
{
  const int m16 = lane & 15, q = lane >> 4;
  const int sh0 = q * 8;
  const int rowB64 = nrowB * 64;
  const int ro0 = ((wv * 2) * 16 + m16) * 64 + q * 8;
  const int ro1 = ro0 + 16 * 64;

  bf16x8 pb0[3], pb1[3];                 // circular queue, slot = G % 3
  #pragma unroll
  for (int g = 0; g < 3; ++g) {          // prologue: G = 0,1,2 (chunk0, ks0)
    const u16* p = wsbase + g * selstride;
    pb0[g] = *(const bf16x8*)(p + ro0);
    pb1[g] = *(const bf16x8*)(p + ro1);
  }
  u64 bw[TT];
  #pragma unroll
  for (int t = 0; t < TT; ++t)
    bw[t] = *(const u64*)(lbits + (t * RR + m16) * bpitch);

  bf16x8 afr[TT];
  for (int kc = 0; kc < nkc; ++kc) {
    const u16* cb = wsbase + kc * rowB64;
    const bool more = (kc + 1 < nkc);
    #pragma unroll
    for (int g = 0; g < 6; ++g) {
      if (g == 0) build_afr(afr, bw, sh0);
      if (g == 3) {
        build_afr(afr, bw, sh0 + 32);
        if (more) {
          #pragma unroll
          for (int t = 0; t < TT; ++t)
            bw[t] = *(const u64*)(lbits + (t * RR + m16) * bpitch + (kc + 1) * 4);
        }
      }
      const int slot = g % 3;
      const bf16x8 b0 = pb0[slot], b1 = pb1[slot];   // waits vmcnt(4)
      // issue loads for G+3: g<3 -> (sel g, ks1) of this chunk; g>=3 -> (sel g-3, ks0) of next
      if (g < 3) {
        const u16* p = cb + g * selstride + 32;
        pb0[slot] = *(const bf16x8*)(p + ro0);
        pb1[slot] = *(const bf16x8*)(p + ro1);
      } else if (more) {
        const u16* p = cb + rowB64 + (g - 3) * selstride;
        pb0[slot] = *(const bf16x8*)(p + ro0);
        pb1[slot] = *(const bf16x8*)(p + ro1);
      }
      #pragma unroll
      for (int t = 0; t < TT; ++t)
        acc[0][t] = __builtin_amdgcn_mfma_f32_16x16x32_bf16(afr[t], b0, acc[0][t], 0, 0, 0);
      #pragma unroll
      for (int t = 0; t < TT; ++t)
        acc[1][t] = __builtin_amdgcn_mfma_f32_16x16x32_bf16(afr[t], b1, acc[1][t], 0, 0, 0);
      SCHED_GRP(0x020, 2);    // the 2 queue loads for G+3 issue early...
      SCHED_GRP(0x008, 10);   // ...before this group's 10 MFMAs retire the slot
    }
  }
}

// LIF recurrence over t; emit spike bits via ballot. 2 col-tiles per wave.
__device__ __forceinline__ void recur_spikes2(
    f32x4 acc[2][TT], const float* __restrict__ bias,
    int lane, int wv, u16* sbits, int spitch)
{
  const int q = lane >> 4, m16 = lane & 15;
  #pragma unroll
  for (int i = 0; i < 2; ++i) {
    int ct = wv * 2 + i;
    int j = ct * 16 + m16;
    float bj = bias[j];
    #pragma unroll
    for (int rg = 0; rg < 4; ++rg) {
      float c = 0.f, v = 0.f, sprev = 0.f;
      #pragma unroll
      for (int t = 0; t < TT; ++t) {
        float u = acc[i][t][rg];
        c = __fadd_rn(__fadd_rn(__fmul_rn(c, 0.5f), u), bj);       // (c*0.5 + u) + b
        float vd = __fmul_rn(v, 0.75f);
        v = __fadd_rn((sprev > 0.5f) ? 0.f : vd, c);               // v*0.75*(1-s) + c
        bool sp = v > 0.5f;
        u64 mask = __ballot(sp);
        if (m16 == 0) {
          int row = q * 4 + rg;
          sbits[(t * RR + row) * spitch + ct] = (u16)(mask >> (q * 16));
        }
        sprev = sp ? 1.f : 0.f;
      }
    }
  }
}

__global__ __launch_bounds__(NTHR) __attribute__((amdgpu_waves_per_eu(4, 4)))
void snn_main(
    const float* __restrict__ b1, const float* __restrict__ b2, const float* __restrict__ bo,
    const float* __restrict__ dec_w, const float* __restrict__ dec_b, const float* __restrict__ log_std,
    const u16* __restrict__ wsW, float* __restrict__ out, int Btot)
{
  __shared__ __align__(16) u16 smem[80 * BP1 + 2 * 80 * BP2 + 2560];  // 25600 B
  u16* encb = smem;                                  // [5*16][BP1]
  u16* s1b  = smem + 80 * BP1;                       // [5*16][BP2]
  u16* s2b  = s1b + 80 * BP2;
  float* soacc = (float*)(s2b + 80 * BP2);           // [16][80] f32

  const int tid  = threadIdx.x;
  const int lane = tid & 63;
  const int wv   = tid >> 6;          // 0..7
  const int r0   = blockIdx.x * RR;

  // ---------- copy this block's spike bit-planes to LDS ----------
  for (int it = tid; it < 800; it += NTHR) {
    const u16* gb = wsW + GB_OFF + r0 * 400;
    uint4 d = *(const uint4*)(gb + it * 8);
    int i8 = it * 8;
    int r = i8 / 400, rem = i8 - r * 400;
    int t = rem / 80, g = rem - t * 80;
    *(uint4*)(&encb[(t * RR + r) * BP1 + g]) = d;
  }
  __syncthreads();

  f32x4 acc[2][TT];
  const f32x4 zero4 = {0.f, 0.f, 0.f, 0.f};
#define ZERO_ACC() { _Pragma("unroll") for (int i = 0; i < 2; ++i) \
                     _Pragma("unroll") for (int t = 0; t < TT; ++t) acc[i][t] = zero4; }

  // ---------- layer 1: [80 x 1280] @ [1280 x 256] (3-way split fused) ----------
  ZERO_ACC();
  gemm2(encb, BP1, wsW, 327680, 20, 256, wv, lane, acc);
  recur_spikes2(acc, b1, lane, wv, s1b, BP2);
  __syncthreads();

  // ---------- layer 2: [80 x 256] @ [256 x 256] ----------
  ZERO_ACC();
  gemm2(s1b, BP2, wsW + W2S_OFF, 65536, 4, 256, wv, lane, acc);
  recur_spikes2(acc, b2, lane, wv, s2b, BP2);
  __syncthreads();

  // ---------- layer 3: [80 x 256] @ [256 x 80(pad96)] — waves 0..2 ----------
  if (wv < 3) {
    ZERO_ACC();
    gemm2(s2b, BP2, wsW + WOS_OFF, 32768, 4, 128, wv, lane, acc);
    const int q = lane >> 4, m16 = lane & 15;
    #pragma unroll
    for (int i = 0; i < 2; ++i) {
      int j = (wv * 2 + i) * 16 + m16;
      bool valid = j < NO;
      float bj = valid ? bo[j] : 0.f;
      #pragma unroll
      for (int rg = 0; rg < 4; ++rg) {
        float c = 0.f, v = 0.f, sprev = 0.f;
        int cnt = 0;
        #pragma unroll
        for (int t = 0; t < TT; ++t) {
          float u = acc[i][t][rg];
          c = __fadd_rn(__fadd_rn(__fmul_rn(c, 0.5f), u), bj);
          float vd = __fmul_rn(v, 0.75f);
          v = __fadd_rn((sprev > 0.5f) ? 0.f : vd, c);
          bool sp = v > 0.5f;
          cnt += sp ? 1 : 0;
          sprev = sp ? 1.f : 0.f;
        }
        if (valid) soacc[(q * 4 + rg) * NO + j] = __fdiv_rn((float)cnt, 5.0f);
      }
    }
  }
  __syncthreads();

  // ---------- decoder: grouped dot + ELU ----------
  if (tid < RR * 8) {
    int r = tid >> 3, a = tid & 7;
    float s = 0.f;
    const float* so = soacc + r * NO + a * 10;
    #pragma unroll
    for (int p = 0; p < 10; ++p)
      s = __fadd_rn(s, __fmul_rn(so[p], dec_w[a * 10 + p]));
    s = __fadd_rn(s, dec_b[a]);
    float mu = (s > 0.f) ? s : expm1f(s);
    out[(r0 + r) * 8 + a] = mu;
  }
  if (blockIdx.x == 0 && tid < 8) {
    out[Btot * 8 + tid] = expf(log_std[tid]);
  }
}

extern "C" void kernel_launch(void* const* d_in, const int* in_sizes, int n_in,
                              void* d_out, int out_size, void* d_ws, size_t ws_size,
                              hipStream_t stream) {
  const float* obs      = (const float*)d_in[0];
  const float* enc_mean = (const float*)d_in[1];
  const float* enc_std  = (const float*)d_in[2];
  const float* W1       = (const float*)d_in[3];
  const float* b1       = (const float*)d_in[4];
  const float* W2       = (const float*)d_in[5];
  const float* b2       = (const float*)d_in[6];
  const float* Wo       = (const float*)d_in[7];
  const float* bo       = (const float*)d_in[8];
  const float* dec_w    = (const float*)d_in[9];
  const float* dec_b    = (const float*)d_in[10];
  const float* log_std  = (const float*)d_in[11];
  u16*   ws  = (u16*)d_ws;
  float* out = (float*)d_out;
  int B = in_sizes[0] / NOBS;   // 8192

  hipLaunchKernelGGL(prep_kernel, dim3(PREP_BLOCKS + ENC_BLOCKS), dim3(256), 0, stream,
                     W1, W2, Wo, obs, enc_mean, enc_std, ws);
  hipLaunchKernelGGL(snn_main, dim3(B / RR), dim3(NTHR), 0, stream,
                     b1, b2, bo, dec_w, dec_b, log_std, ws, out, B);
}

// Round 13
// 237.872 us; speedup vs baseline: 1.1732x; 1.1732x over previous
//
#include <hip/hip_runtime.h>

typedef unsigned short u16;
typedef unsigned int   u32;
typedef unsigned long long u64;
typedef __attribute__((ext_vector_type(8))) short bf16x8;
typedef __attribute__((ext_vector_type(4))) float f32x4;

#define NOBS 128
#define NN   1280
#define NH   256
#define NO   80
#define TT   5
#define RR   16          // batch rows per block
#define NTHR 512         // 8 waves/block, 2 col-tiles per wave
#define BP1  88          // layer1 bits LDS pitch (u16)
#define BP2  20          // layer2/3 bits pitch (u16)

// ws layout (u16 units), 3-way bf16 split (hi | mid | lo grouped per matrix):
//   W1s [3][20][256][64] @0 ; W2s [3][4][256][64] @983040 ; Wos [3][4][128][64] @1179648
//   gbits [8192 rows][5 t][80] @1277952  (spike bit-planes, 16 bits/u16 word)
#define W1TOT   983040
#define W2S_OFF 983040
#define WOS_OFF 1179648
#define WS_TOTAL 1277952
#define GB_OFF  WS_TOTAL

#define PREP_BLOCKS 4992          // WS_TOTAL/256
#define ENC_BLOCKS  2560          // 8192*80/256 (one thread per u16 bit-word)

__device__ __forceinline__ float bf2f(u16 u) {
  union { u32 i; float f; } x; x.i = ((u32)u) << 16; return x.f;
}
__device__ __forceinline__ u16 f2bf(float f) {
  union { float f; u32 i; } x; x.f = f;
  u32 i = x.i + 0x7FFFu + ((x.i >> 16) & 1u);   // RNE
  return (u16)(i >> 16);
}

// 3-way bf16 split: w ~= hi + mid + lo, residual <= 2^-27 |w|.
__device__ __forceinline__ u16 split3(float w, int sel) {
  u16 hi = f2bf(w);
  if (sel == 0) return hi;
  float r1 = __fsub_rn(w, bf2f(hi));        // exact
  u16 mid = f2bf(r1);
  if (sel == 1) return mid;
  float r2 = __fsub_rn(r1, bf2f(mid));      // exact
  return f2bf(r2);
}

// Inline near-correctly-rounded f32 exp via f64 degree-11 Taylor.
__device__ __forceinline__ float exp_cr(float arg) {
  double xa = (double)arg;
  double nd = __builtin_rint(xa * 1.4426950408889634074);
  double r  = fma(nd, -6.93147180369123816490e-01, xa);
  r         = fma(nd, -1.90821492927058770002e-10, r);
  double p = 2.50521083854417187751e-08;
  p = fma(p, r, 2.75573192239858906526e-07);
  p = fma(p, r, 2.75573192239858906526e-06);
  p = fma(p, r, 2.48015873015873015873e-05);
  p = fma(p, r, 1.98412698412698412698e-04);
  p = fma(p, r, 1.38888888888888888889e-03);
  p = fma(p, r, 8.33333333333333333333e-03);
  p = fma(p, r, 4.16666666666666666667e-02);
  p = fma(p, r, 1.66666666666666666667e-01);
  p = fma(p, r, 0.5);
  p = fma(p, r, 1.0);
  p = fma(p, r, 1.0);
  int n = (int)nd;
  union { u64 u; double d; } s;
  s.u = ((u64)(u32)(n + 1023)) << 52;
  return (n < -150) ? 0.f : (float)(s.d * p);
}

// Fused prep: blocks [0,4992) split weights; blocks [4992,7552) run the encoder.
__global__ __launch_bounds__(256) void prep_kernel(
    const float* __restrict__ W1, const float* __restrict__ W2,
    const float* __restrict__ Wo,
    const float* __restrict__ obs, const float* __restrict__ enc_mean,
    const float* __restrict__ enc_std, u16* __restrict__ ws)
{
  int bid = blockIdx.x;
  if (bid < PREP_BLOCKS) {
    int i = bid * 256 + threadIdx.x;
    if (i < W1TOT) {                          // W1 [256][1280]
      int sel = i / 327680, rem = i - sel * 327680;
      int kc = rem >> 14, r = rem & 16383, j = r >> 6, kk = r & 63;
      ws[i] = split3(W1[j * 1280 + kc * 64 + kk], sel);
    } else if (i < WOS_OFF) {                 // W2 [256][256]
      int i2 = i - W2S_OFF;
      int sel = i2 >> 16, rem = i2 & 65535;
      int kc = rem >> 14, j = (rem >> 6) & 255, kk = rem & 63;
      ws[i] = split3(W2[j * 256 + kc * 64 + kk], sel);
    } else {                                  // Wo [80][256] padded to 128 rows
      int i3 = i - WOS_OFF;
      int sel = i3 >> 15, rem = i3 & 32767;
      int kc = rem >> 13, j = (rem >> 6) & 127, kk = rem & 63;
      float w = (j < NO) ? Wo[j * 256 + kc * 64 + kk] : 0.f;
      ws[i] = split3(w, sel);
    }
    return;
  }
  // ---- encoder ----
  int gid = (bid - PREP_BLOCKS) * 256 + threadIdx.x;   // < 8192*80
  int r = gid / 80, w = gid - (gid / 80) * 80;
  const float* obsrow = obs + r * NOBS;
  u32 wbits[TT] = {0, 0, 0, 0, 0};
  #pragma unroll
  for (int e = 0; e < 16; ++e) {
    int k = w * 16 + e;
    int f = k / 10;
    float x  = obsrow[f];
    float m  = enc_mean[k];
    float sd = enc_std[k];
    float d  = __fsub_rn(x, m);
    float arg = __fdiv_rn(__fmul_rn(-0.5f, __fmul_rn(d, d)), __fmul_rn(sd, sd));
    float a = exp_cr(arg);
    float v = 0.f;
    #pragma unroll
    for (int t = 0; t < TT; ++t) {
      v = __fadd_rn(v, a);
      if (v > 0.999f) { wbits[t] |= (1u << e); v = __fsub_rn(v, 0.999f); }
    }
  }
  u16* gb = ws + GB_OFF + r * 400 + w;       // [row][t][80]
  #pragma unroll
  for (int t = 0; t < TT; ++t) gb[t * 80] = (u16)wbits[t];
}

// Expand 8 spike bits (one byte) -> bf16x8 A-fragment; mul-spread, 4 VALU/u32.
__device__ __forceinline__ void build_afr(bf16x8 afr[TT], const u64 bw[TT], int sh) {
  #pragma unroll
  for (int t = 0; t < TT; ++t) {
    u32 b = (u32)(bw[t] >> sh) & 0xFFu;
    union { u32 u[4]; bf16x8 v; } x;
    #pragma unroll
    for (int i = 0; i < 4; ++i) {
      u32 two = (b >> (2 * i)) & 3u;
      x.u[i] = ((two * 0x8001u) & 0x00010001u) * 0x3F80u;
    }
    afr[t] = x.v;
  }
}

// Barrier-free merged-split GEMM, 2 col-tiles/wave, single merged accumulator.
// Depth-3 B pipeline (circular queue, slot = G % 3). Sequential kc order
// (accumulation chain is load-bearing — see R12 post-mortem). ct0 = col-tile
// pair index (may be block-swizzled; accumulation order per column invariant).
__device__ __forceinline__ void gemm2(
    const u16* __restrict__ lbits, int bpitch,
    const u16* __restrict__ wsbase, int selstride, int nkc, int nrowB,
    int ct0, int lane, f32x4 acc[2][TT])
{
  const int m16 = lane & 15, q = lane >> 4;
  const int sh0 = q * 8;
  const int rowB64 = nrowB * 64;
  const int ro0 = ((ct0 * 2) * 16 + m16) * 64 + q * 8;
  const int ro1 = ro0 + 16 * 64;

  bf16x8 pb0[3], pb1[3];                 // circular queue, slot = G % 3
  #pragma unroll
  for (int g = 0; g < 3; ++g) {          // prologue: G = 0,1,2 (chunk0, ks0)
    const u16* p = wsbase + g * selstride;
    pb0[g] = *(const bf16x8*)(p + ro0);
    pb1[g] = *(const bf16x8*)(p + ro1);
  }
  u64 bw[TT];
  #pragma unroll
  for (int t = 0; t < TT; ++t)
    bw[t] = *(const u64*)(lbits + (t * RR + m16) * bpitch);

  bf16x8 afr[TT];
  for (int kc = 0; kc < nkc; ++kc) {
    const u16* cb = wsbase + kc * rowB64;
    const bool more = (kc + 1 < nkc);
    #pragma unroll
    for (int g = 0; g < 6; ++g) {
      if (g == 0) build_afr(afr, bw, sh0);
      if (g == 3) {
        build_afr(afr, bw, sh0 + 32);
        if (more) {
          #pragma unroll
          for (int t = 0; t < TT; ++t)
            bw[t] = *(const u64*)(lbits + (t * RR + m16) * bpitch + (kc + 1) * 4);
        }
      }
      const int slot = g % 3;
      const bf16x8 b0 = pb0[slot], b1 = pb1[slot];
      // issue loads for G+3: g<3 -> (sel g, ks1) this chunk; g>=3 -> (sel g-3, ks0) next
      if (g < 3) {
        const u16* p = cb + g * selstride + 32;
        pb0[slot] = *(const bf16x8*)(p + ro0);
        pb1[slot] = *(const bf16x8*)(p + ro1);
      } else if (more) {
        const u16* p = cb + rowB64 + (g - 3) * selstride;
        pb0[slot] = *(const bf16x8*)(p + ro0);
        pb1[slot] = *(const bf16x8*)(p + ro1);
      }
      #pragma unroll
      for (int t = 0; t < TT; ++t)
        acc[0][t] = __builtin_amdgcn_mfma_f32_16x16x32_bf16(afr[t], b0, acc[0][t], 0, 0, 0);
      #pragma unroll
      for (int t = 0; t < TT; ++t)
        acc[1][t] = __builtin_amdgcn_mfma_f32_16x16x32_bf16(afr[t], b1, acc[1][t], 0, 0, 0);
    }
  }
}

// LIF recurrence over t; emit spike bits via ballot. 2 col-tiles per wave (ct0 pair).
__device__ __forceinline__ void recur_spikes2(
    f32x4 acc[2][TT], const float* __restrict__ bias,
    int lane, int ct0, u16* sbits, int spitch)
{
  const int q = lane >> 4, m16 = lane & 15;
  #pragma unroll
  for (int i = 0; i < 2; ++i) {
    int ct = ct0 * 2 + i;
    int j = ct * 16 + m16;
    float bj = bias[j];
    #pragma unroll
    for (int rg = 0; rg < 4; ++rg) {
      float c = 0.f, v = 0.f, sprev = 0.f;
      #pragma unroll
      for (int t = 0; t < TT; ++t) {
        float u = acc[i][t][rg];
        c = __fadd_rn(__fadd_rn(__fmul_rn(c, 0.5f), u), bj);       // (c*0.5 + u) + b
        float vd = __fmul_rn(v, 0.75f);
        v = __fadd_rn((sprev > 0.5f) ? 0.f : vd, c);               // v*0.75*(1-s) + c
        bool sp = v > 0.5f;
        u64 mask = __ballot(sp);
        if (m16 == 0) {
          int row = q * 4 + rg;
          sbits[(t * RR + row) * spitch + ct] = (u16)(mask >> (q * 16));
        }
        sprev = sp ? 1.f : 0.f;
      }
    }
  }
}

__global__ __launch_bounds__(NTHR, 4) void snn_main(
    const float* __restrict__ b1, const float* __restrict__ b2, const float* __restrict__ bo,
    const float* __restrict__ dec_w, const float* __restrict__ dec_b, const float* __restrict__ log_std,
    const u16* __restrict__ wsW, float* __restrict__ out, int Btot)
{
  __shared__ __align__(16) u16 smem[80 * BP1 + 2 * 80 * BP2 + 2560];  // 25600 B
  u16* encb = smem;                                  // [5*16][BP1]
  u16* s1b  = smem + 80 * BP1;                       // [5*16][BP2]
  u16* s2b  = s1b + 80 * BP2;
  float* soacc = (float*)(s2b + 80 * BP2);           // [16][80] f32

  const int tid  = threadIdx.x;
  const int lane = tid & 63;
  const int wv   = tid >> 6;          // 0..7
  const int bid  = blockIdx.x;
  const int r0   = bid * RR;

  // Convoy breaker (numerics-safe): rotate col-tile-pair assignment per block.
  // Column j's accumulation chain is unchanged; only the owning wave differs,
  // so co-scheduled blocks fetch different weight fragments at the same phase.
  const int cts = (wv + bid) & 7;

  // ---------- copy this block's spike bit-planes to LDS ----------
  for (int it = tid; it < 800; it += NTHR) {
    const u16* gb = wsW + GB_OFF + r0 * 400;
    uint4 d = *(const uint4*)(gb + it * 8);
    int i8 = it * 8;
    int r = i8 / 400, rem = i8 - r * 400;
    int t = rem / 80, g = rem - t * 80;
    *(uint4*)(&encb[(t * RR + r) * BP1 + g]) = d;
  }
  __syncthreads();

  f32x4 acc[2][TT];
  const f32x4 zero4 = {0.f, 0.f, 0.f, 0.f};
#define ZERO_ACC() { _Pragma("unroll") for (int i = 0; i < 2; ++i) \
                     _Pragma("unroll") for (int t = 0; t < TT; ++t) acc[i][t] = zero4; }

  // ---------- layer 1: [80 x 1280] @ [1280 x 256] (3-way split fused) ----------
  ZERO_ACC();
  gemm2(encb, BP1, wsW, 327680, 20, 256, cts, lane, acc);
  recur_spikes2(acc, b1, lane, cts, s1b, BP2);
  __syncthreads();

  // ---------- layer 2: [80 x 256] @ [256 x 256] ----------
  ZERO_ACC();
  gemm2(s1b, BP2, wsW + W2S_OFF, 65536, 4, 256, cts, lane, acc);
  recur_spikes2(acc, b2, lane, cts, s2b, BP2);
  __syncthreads();

  // ---------- layer 3: [80 x 256] @ [256 x 80(pad96)] — waves 0..2, unswizzled ----------
  if (wv < 3) {
    ZERO_ACC();
    gemm2(s2b, BP2, wsW + WOS_OFF, 32768, 4, 128, wv, lane, acc);
    const int q = lane >> 4, m16 = lane & 15;
    #pragma unroll
    for (int i = 0; i < 2; ++i) {
      int j = (wv * 2 + i) * 16 + m16;
      bool valid = j < NO;
      float bj = valid ? bo[j] : 0.f;
      #pragma unroll
      for (int rg = 0; rg < 4; ++rg) {
        float c = 0.f, v = 0.f, sprev = 0.f;
        int cnt = 0;
        #pragma unroll
        for (int t = 0; t < TT; ++t) {
          float u = acc[i][t][rg];
          c = __fadd_rn(__fadd_rn(__fmul_rn(c, 0.5f), u), bj);
          float vd = __fmul_rn(v, 0.75f);
          v = __fadd_rn((sprev > 0.5f) ? 0.f : vd, c);
          bool sp = v > 0.5f;
          cnt += sp ? 1 : 0;
          sprev = sp ? 1.f : 0.f;
        }
        if (valid) soacc[(q * 4 + rg) * NO + j] = __fdiv_rn((float)cnt, 5.0f);
      }
    }
  }
  __syncthreads();

  // ---------- decoder: grouped dot + ELU ----------
  if (tid < RR * 8) {
    int r = tid >> 3, a = tid & 7;
    float s = 0.f;
    const float* so = soacc + r * NO + a * 10;
    #pragma unroll
    for (int p = 0; p < 10; ++p)
      s = __fadd_rn(s, __fmul_rn(so[p], dec_w[a * 10 + p]));
    s = __fadd_rn(s, dec_b[a]);
    float mu = (s > 0.f) ? s : expm1f(s);
    out[(r0 + r) * 8 + a] = mu;
  }
  if (bid == 0 && tid < 8) {
    out[Btot * 8 + tid] = expf(log_std[tid]);
  }
}

extern "C" void kernel_launch(void* const* d_in, const int* in_sizes, int n_in,
                              void* d_out, int out_size, void* d_ws, size_t ws_size,
                              hipStream_t stream) {
  const float* obs      = (const float*)d_in[0];
  const float* enc_mean = (const float*)d_in[1];
  const float* enc_std  = (const float*)d_in[2];
  const float* W1       = (const float*)d_in[3];
  const float* b1       = (const float*)d_in[4];
  const float* W2       = (const float*)d_in[5];
  const float* b2       = (const float*)d_in[6];
  const float* Wo       = (const float*)d_in[7];
  const float* bo       = (const float*)d_in[8];
  const float* dec_w    = (const float*)d_in[9];
  const float* dec_b    = (const float*)d_in[10];
  const float* log_std  = (const float*)d_in[11];
  u16*   ws  = (u16*)d_ws;
  float* out = (float*)d_out;
  int B = in_sizes[0] / NOBS;   // 8192

  hipLaunchKernelGGL(prep_kernel, dim3(PREP_BLOCKS + ENC_BLOCKS), dim3(256), 0, stream,
                     W1, W2, Wo, obs, enc_mean, enc_std, ws);
  hipLaunchKernelGGL(snn_main, dim3(B / RR), dim3(NTHR), 0, stream,
                     b1, b2, bo, dec_w, dec_b, log_std, ws, out, B);
}

// Round 14
// 199.788 us; speedup vs baseline: 1.3968x; 1.1906x over previous
//
#include <hip/hip_runtime.h>

typedef unsigned short u16;
typedef unsigned int   u32;
typedef unsigned long long u64;
typedef __attribute__((ext_vector_type(8))) short bf16x8;
typedef __attribute__((ext_vector_type(4))) float f32x4;

#define NOBS 128
#define NN   1280
#define NH   256
#define NO   80
#define TT   5
#define RR   32          // batch rows per block (10 row-tiles of 16, t-folded)
#define NTHR 1024        // 16 waves/block, 1 col-tile per wave
#define BP1  88          // layer1 bits LDS pitch (u16)
#define BP2  20          // layer2/3 bits pitch (u16)

// ws layout (u16 units), stage-contiguous: [kc][ks][sel][rows][32]
//   W1s [20][2][3][256][32] @0 ; W2s [4][2][3][256][32] @983040 ;
//   Wos [4][2][3][128][32] @1179648 (rows padded to 128)
//   gbits [8192 rows][5 t][80] @1277952  (spike bit-planes)
#define W1TOT   983040
#define W2S_OFF 983040
#define WOS_OFF 1179648
#define WS_TOTAL 1277952
#define GB_OFF  WS_TOTAL

#define PREP_BLOCKS 4992          // WS_TOTAL/256
#define ENC_BLOCKS  2560          // 8192*80/256

__device__ __forceinline__ float bf2f(u16 u) {
  union { u32 i; float f; } x; x.i = ((u32)u) << 16; return x.f;
}
__device__ __forceinline__ u16 f2bf(float f) {
  union { float f; u32 i; } x; x.f = f;
  u32 i = x.i + 0x7FFFu + ((x.i >> 16) & 1u);   // RNE
  return (u16)(i >> 16);
}

// 3-way bf16 split: w ~= hi + mid + lo, residual <= 2^-27 |w|.
__device__ __forceinline__ u16 split3(float w, int sel) {
  u16 hi = f2bf(w);
  if (sel == 0) return hi;
  float r1 = __fsub_rn(w, bf2f(hi));        // exact
  u16 mid = f2bf(r1);
  if (sel == 1) return mid;
  float r2 = __fsub_rn(r1, bf2f(mid));      // exact
  return f2bf(r2);
}

// Inline near-correctly-rounded f32 exp via f64 degree-11 Taylor.
__device__ __forceinline__ float exp_cr(float arg) {
  double xa = (double)arg;
  double nd = __builtin_rint(xa * 1.4426950408889634074);
  double r  = fma(nd, -6.93147180369123816490e-01, xa);
  r         = fma(nd, -1.90821492927058770002e-10, r);
  double p = 2.50521083854417187751e-08;
  p = fma(p, r, 2.75573192239858906526e-07);
  p = fma(p, r, 2.75573192239858906526e-06);
  p = fma(p, r, 2.48015873015873015873e-05);
  p = fma(p, r, 1.98412698412698412698e-04);
  p = fma(p, r, 1.38888888888888888889e-03);
  p = fma(p, r, 8.33333333333333333333e-03);
  p = fma(p, r, 4.16666666666666666667e-02);
  p = fma(p, r, 1.66666666666666666667e-01);
  p = fma(p, r, 0.5);
  p = fma(p, r, 1.0);
  p = fma(p, r, 1.0);
  int n = (int)nd;
  union { u64 u; double d; } s;
  s.u = ((u64)(u32)(n + 1023)) << 52;
  return (n < -150) ? 0.f : (float)(s.d * p);
}

// Fused prep: blocks [0,4992) split weights into stage-contiguous layout;
// blocks [4992,7552) run the population encoder.
__global__ __launch_bounds__(256) void prep_kernel(
    const float* __restrict__ W1, const float* __restrict__ W2,
    const float* __restrict__ Wo,
    const float* __restrict__ obs, const float* __restrict__ enc_mean,
    const float* __restrict__ enc_std, u16* __restrict__ ws)
{
  int bid = blockIdx.x;
  if (bid < PREP_BLOCKS) {
    int i = bid * 256 + threadIdx.x;
    if (i < W1TOT) {                          // W1 [256][1280] -> [kc][ks][sel][j][32]
      int kc = i / 49152, r = i - kc * 49152;
      int ks = r / 24576, r2 = r - ks * 24576;
      int sel = r2 / 8192, r3 = r2 & 8191;
      int j = r3 >> 5, kk = r3 & 31;
      ws[i] = split3(W1[j * 1280 + kc * 64 + ks * 32 + kk], sel);
    } else if (i < WOS_OFF) {                 // W2 [256][256]
      int i2 = i - W2S_OFF;
      int kc = i2 / 49152, r = i2 - kc * 49152;
      int ks = r / 24576, r2 = r - ks * 24576;
      int sel = r2 / 8192, r3 = r2 & 8191;
      int j = r3 >> 5, kk = r3 & 31;
      ws[i] = split3(W2[j * 256 + kc * 64 + ks * 32 + kk], sel);
    } else {                                  // Wo [80][256] padded to 128 rows
      int i3 = i - WOS_OFF;
      int kc = i3 / 24576, r = i3 - kc * 24576;
      int ks = r / 12288, r2 = r - ks * 12288;
      int sel = r2 / 4096, r3 = r2 & 4095;
      int j = r3 >> 5, kk = r3 & 31;
      float w = (j < NO) ? Wo[j * 256 + kc * 64 + ks * 32 + kk] : 0.f;
      ws[i] = split3(w, sel);
    }
    return;
  }
  // ---- encoder ----
  int gid = (bid - PREP_BLOCKS) * 256 + threadIdx.x;   // < 8192*80
  int r = gid / 80, w = gid - (gid / 80) * 80;
  const float* obsrow = obs + r * NOBS;
  u32 wbits[TT] = {0, 0, 0, 0, 0};
  #pragma unroll
  for (int e = 0; e < 16; ++e) {
    int k = w * 16 + e;
    int f = k / 10;
    float x  = obsrow[f];
    float m  = enc_mean[k];
    float sd = enc_std[k];
    float d  = __fsub_rn(x, m);
    float arg = __fdiv_rn(__fmul_rn(-0.5f, __fmul_rn(d, d)), __fmul_rn(sd, sd));
    float a = exp_cr(arg);
    float v = 0.f;
    #pragma unroll
    for (int t = 0; t < TT; ++t) {
      v = __fadd_rn(v, a);
      if (v > 0.999f) { wbits[t] |= (1u << e); v = __fsub_rn(v, 0.999f); }
    }
  }
  u16* gb = ws + GB_OFF + r * 400 + w;       // [row][t][80]
  #pragma unroll
  for (int t = 0; t < TT; ++t) gb[t * 80] = (u16)wbits[t];
}

// Async DMA of one stage (nch KB) into LDS: wave-uniform LDS base + lane*16B.
__device__ __forceinline__ void dma_stage(const u16* __restrict__ src, u16* dst,
                                          int nch, int wv, int lane) {
  if (nch == 48) {
    #pragma unroll
    for (int c = 0; c < 3; ++c) {
      int ch = wv + c * 16;
      __builtin_amdgcn_global_load_lds((const u32*)(src + ch * 512 + lane * 8),
                                       (u32*)(dst + ch * 512), 16, 0, 0);
    }
  } else {                                   // 24 chunks: waves 0..7
    if (wv < 8) {
      #pragma unroll
      for (int c = 0; c < 3; ++c) {
        int ch = wv + c * 8;
        __builtin_amdgcn_global_load_lds((const u32*)(src + ch * 512 + lane * 8),
                                         (u32*)(dst + ch * 512), 16, 0, 0);
      }
    }
  }
}

// Staged GEMM: per stage (kc,ks) all 3 sel-planes of B live in LDS (48KB DMA,
// double-buffered, ONE barrier per stage). A built in-register from bit-planes
// once per stage, reused by 3 sels -> 30 MFMAs per wave per barrier.
// Per-column accumulation order identical to R13: kc:(ks0:hi,mid,lo),(ks1:...).
__device__ __forceinline__ void gemm_staged(
    const u16* lbits, int bpitch,
    const u16* __restrict__ wsbase, int nkc, int stgsz, int selblk, int nch,
    u16* buf0, u16* buf1, int wv, int lane, bool active, f32x4 acc[10])
{
  const int m16 = lane & 15, q = lane >> 4;
  const int fro = (wv * 16 + m16) * 32 + q * 8;   // fragment offset in sel-block
  const int sh  = q * 8;

  dma_stage(wsbase, buf0, nch, wv, lane);
  __syncthreads();                                 // drains DMA0 (+ bits copy)

  const int nst = nkc * 2;
  for (int st = 0; st < nst; ++st) {
    u16* cur = (st & 1) ? buf1 : buf0;
    u16* nxt = (st & 1) ? buf0 : buf1;
    if (st + 1 < nst) dma_stage(wsbase + (st + 1) * stgsz, nxt, nch, wv, lane);
    if (active) {
      const int kc = st >> 1, ks = st & 1;
      bf16x8 afr[10];
      #pragma unroll
      for (int rt = 0; rt < 10; ++rt) {
        u32 bwv = *(const u32*)(lbits +
            ((rt >> 1) * RR + (rt & 1) * 16 + m16) * bpitch + kc * 4 + ks * 2);
        u32 b = (bwv >> sh) & 0xFFu;
        union { u32 u[4]; bf16x8 v; } x;
        #pragma unroll
        for (int i = 0; i < 4; ++i)
          x.u[i] = ((((b >> (2 * i)) & 3u) * 0x8001u) & 0x00010001u) * 0x3F80u;
        afr[rt] = x.v;
      }
      #pragma unroll
      for (int sel = 0; sel < 3; ++sel) {
        const bf16x8 bfr = *(const bf16x8*)(cur + sel * selblk + fro);
        #pragma unroll
        for (int rt = 0; rt < 10; ++rt)
          acc[rt] = __builtin_amdgcn_mfma_f32_16x16x32_bf16(afr[rt], bfr, acc[rt], 0, 0, 0);
      }
    }
    __syncthreads();   // stage n's compute done; DMA n+1 (issued ~a stage ago) drained
  }
}

// LIF recurrence over t (rows h*16 + q*4+rg, acc tile rt = t*2+h); ballot->bits.
__device__ __forceinline__ void recur_spikes32(
    f32x4 acc[10], const float* __restrict__ bias,
    int lane, int wv, u16* sbits, int spitch)
{
  const int q = lane >> 4, m16 = lane & 15;
  int j = wv * 16 + m16;
  float bj = bias[j];
  #pragma unroll
  for (int h = 0; h < 2; ++h) {
    #pragma unroll
    for (int rg = 0; rg < 4; ++rg) {
      float c = 0.f, v = 0.f, sprev = 0.f;
      #pragma unroll
      for (int t = 0; t < TT; ++t) {
        float u = acc[t * 2 + h][rg];
        c = __fadd_rn(__fadd_rn(__fmul_rn(c, 0.5f), u), bj);       // (c*0.5 + u) + b
        float vd = __fmul_rn(v, 0.75f);
        v = __fadd_rn((sprev > 0.5f) ? 0.f : vd, c);               // v*0.75*(1-s) + c
        bool sp = v > 0.5f;
        u64 mask = __ballot(sp);
        if (m16 == 0) {
          int row = h * 16 + q * 4 + rg;
          sbits[(t * RR + row) * spitch + wv] = (u16)(mask >> (q * 16));
        }
        sprev = sp ? 1.f : 0.f;
      }
    }
  }
}

__global__ __launch_bounds__(NTHR) void snn_main(
    const float* __restrict__ b1, const float* __restrict__ b2, const float* __restrict__ bo,
    const float* __restrict__ dec_w, const float* __restrict__ dec_b, const float* __restrict__ log_std,
    const u16* __restrict__ wsW, float* __restrict__ out, int Btot)
{
  __shared__ __align__(16) u16 smem[63232];          // 126,464 B (1 block/CU)
  u16* buf0 = smem;                                  // [24576] stage buffer A
  u16* buf1 = smem + 24576;                          // [24576] stage buffer B
  u16* encb = smem + 49152;                          // [5t*32r][BP1] bits
  u16* s1b  = encb;                                  // alias (encb dead after L1)
  u16* s2b  = encb + TT * RR * BP2;                  // +3200
  float* soacc = (float*)(encb + 2 * TT * RR * BP2); // [32][80] f32

  const int tid  = threadIdx.x;
  const int lane = tid & 63;
  const int wv   = tid >> 6;          // 0..15
  const int r0   = blockIdx.x * RR;

  // ---------- copy this block's spike bit-planes (32 rows x 5 t x 80 u16) ----------
  for (int it = tid; it < 1600; it += NTHR) {
    const u16* gb = wsW + GB_OFF + r0 * 400;
    uint4 d = *(const uint4*)(gb + it * 8);
    int i8 = it * 8;
    int r = i8 / 400, rem = i8 - r * 400;
    int t = rem / 80, g = rem - t * 80;
    *(uint4*)(&encb[(t * RR + r) * BP1 + g]) = d;
  }
  // (visibility guaranteed by gemm_staged's post-DMA barrier)

  f32x4 acc[10];
  const f32x4 zero4 = {0.f, 0.f, 0.f, 0.f};
#define ZERO_ACC() { _Pragma("unroll") for (int rt = 0; rt < 10; ++rt) acc[rt] = zero4; }

  // ---------- layer 1: [160 x 1280] @ [1280 x 256] (3-way split fused) ----------
  ZERO_ACC();
  gemm_staged(encb, BP1, wsW, 20, 24576, 8192, 48, buf0, buf1, wv, lane, true, acc);
  recur_spikes32(acc, b1, lane, wv, s1b, BP2);
  __syncthreads();

  // ---------- layer 2: [160 x 256] @ [256 x 256] ----------
  ZERO_ACC();
  gemm_staged(s1b, BP2, wsW + W2S_OFF, 4, 24576, 8192, 48, buf0, buf1, wv, lane, true, acc);
  recur_spikes32(acc, b2, lane, wv, s2b, BP2);
  __syncthreads();

  // ---------- layer 3: [160 x 256] @ [256 x 80(pad128)] — waves 0..4 ----------
  ZERO_ACC();
  gemm_staged(s2b, BP2, wsW + WOS_OFF, 4, 12288, 4096, 24, buf0, buf1, wv, lane, wv < 5, acc);
  if (wv < 5) {
    const int q = lane >> 4, m16 = lane & 15;
    int j = wv * 16 + m16;                    // < 80 always
    float bj = bo[j];
    #pragma unroll
    for (int h = 0; h < 2; ++h) {
      #pragma unroll
      for (int rg = 0; rg < 4; ++rg) {
        float c = 0.f, v = 0.f, sprev = 0.f;
        int cnt = 0;
        #pragma unroll
        for (int t = 0; t < TT; ++t) {
          float u = acc[t * 2 + h][rg];
          c = __fadd_rn(__fadd_rn(__fmul_rn(c, 0.5f), u), bj);
          float vd = __fmul_rn(v, 0.75f);
          v = __fadd_rn((sprev > 0.5f) ? 0.f : vd, c);
          bool sp = v > 0.5f;
          cnt += sp ? 1 : 0;
          sprev = sp ? 1.f : 0.f;
        }
        soacc[(h * 16 + q * 4 + rg) * NO + j] = __fdiv_rn((float)cnt, 5.0f);
      }
    }
  }
  __syncthreads();

  // ---------- decoder: grouped dot + ELU ----------
  if (tid < RR * 8) {
    int r = tid >> 3, a = tid & 7;
    float s = 0.f;
    const float* so = soacc + r * NO + a * 10;
    #pragma unroll
    for (int p = 0; p < 10; ++p)
      s = __fadd_rn(s, __fmul_rn(so[p], dec_w[a * 10 + p]));
    s = __fadd_rn(s, dec_b[a]);
    float mu = (s > 0.f) ? s : expm1f(s);
    out[(r0 + r) * 8 + a] = mu;
  }
  if (blockIdx.x == 0 && tid < 8) {
    out[Btot * 8 + tid] = expf(log_std[tid]);
  }
}

extern "C" void kernel_launch(void* const* d_in, const int* in_sizes, int n_in,
                              void* d_out, int out_size, void* d_ws, size_t ws_size,
                              hipStream_t stream) {
  const float* obs      = (const float*)d_in[0];
  const float* enc_mean = (const float*)d_in[1];
  const float* enc_std  = (const float*)d_in[2];
  const float* W1       = (const float*)d_in[3];
  const float* b1       = (const float*)d_in[4];
  const float* W2       = (const float*)d_in[5];
  const float* b2       = (const float*)d_in[6];
  const float* Wo       = (const float*)d_in[7];
  const float* bo       = (const float*)d_in[8];
  const float* dec_w    = (const float*)d_in[9];
  const float* dec_b    = (const float*)d_in[10];
  const float* log_std  = (const float*)d_in[11];
  u16*   ws  = (u16*)d_ws;
  float* out = (float*)d_out;
  int B = in_sizes[0] / NOBS;   // 8192

  hipLaunchKernelGGL(prep_kernel, dim3(PREP_BLOCKS + ENC_BLOCKS), dim3(256), 0, stream,
                     W1, W2, Wo, obs, enc_mean, enc_std, ws);
  hipLaunchKernelGGL(snn_main, dim3(B / RR), dim3(NTHR), 0, stream,
                     b1, b2, bo, dec_w, dec_b, log_std, ws, out, B);
}

// Round 15
// 199.644 us; speedup vs baseline: 1.3978x; 1.0007x over previous
//
#include <hip/hip_runtime.h>

typedef unsigned short u16;
typedef unsigned int   u32;
typedef unsigned long long u64;
typedef __attribute__((ext_vector_type(8))) short bf16x8;
typedef __attribute__((ext_vector_type(4))) float f32x4;

#define NOBS 128
#define NN   1280
#define NH   256
#define NO   80
#define TT   5
#define RR   16          // batch rows per block
#define NTHR 512         // 8 waves/block, 2 col-tiles per wave
#define BP1  88          // layer1 bits LDS pitch (u16)
#define BP2  20          // layer2/3 bits pitch (u16)

// ws layout (u16 units), stage-contiguous: [kc][ks][sel][rows][32], rows
// XOR-swizzled within (see prep). W1s [20][2][3][256][32] @0 ;
// W2s [4][2][3][256][32] @983040 ; Wos [4][2][3][128][32] @1179648 (pad128)
// gbits [8192 rows][5 t][80] @1277952
#define W1TOT   983040
#define W2S_OFF 983040
#define WOS_OFF 1179648
#define WS_TOTAL 1277952
#define GB_OFF  WS_TOTAL

#define PREP_BLOCKS 4992          // WS_TOTAL/256
#define ENC_BLOCKS  2560          // 8192*80/256

__device__ __forceinline__ float bf2f(u16 u) {
  union { u32 i; float f; } x; x.i = ((u32)u) << 16; return x.f;
}
__device__ __forceinline__ u16 f2bf(float f) {
  union { float f; u32 i; } x; x.f = f;
  u32 i = x.i + 0x7FFFu + ((x.i >> 16) & 1u);   // RNE
  return (u16)(i >> 16);
}

// 3-way bf16 split: w ~= hi + mid + lo, residual <= 2^-27 |w|.
__device__ __forceinline__ u16 split3(float w, int sel) {
  u16 hi = f2bf(w);
  if (sel == 0) return hi;
  float r1 = __fsub_rn(w, bf2f(hi));        // exact
  u16 mid = f2bf(r1);
  if (sel == 1) return mid;
  float r2 = __fsub_rn(r1, bf2f(mid));      // exact
  return f2bf(r2);
}

// Inline near-correctly-rounded f32 exp via f64 degree-11 Taylor.
__device__ __forceinline__ float exp_cr(float arg) {
  double xa = (double)arg;
  double nd = __builtin_rint(xa * 1.4426950408889634074);
  double r  = fma(nd, -6.93147180369123816490e-01, xa);
  r         = fma(nd, -1.90821492927058770002e-10, r);
  double p = 2.50521083854417187751e-08;
  p = fma(p, r, 2.75573192239858906526e-07);
  p = fma(p, r, 2.75573192239858906526e-06);
  p = fma(p, r, 2.48015873015873015873e-05);
  p = fma(p, r, 1.98412698412698412698e-04);
  p = fma(p, r, 1.38888888888888888889e-03);
  p = fma(p, r, 8.33333333333333333333e-03);
  p = fma(p, r, 4.16666666666666666667e-02);
  p = fma(p, r, 1.66666666666666666667e-01);
  p = fma(p, r, 0.5);
  p = fma(p, r, 1.0);
  p = fma(p, r, 1.0);
  int n = (int)nd;
  union { u64 u; double d; } s;
  s.u = ((u64)(u32)(n + 1023)) << 52;
  return (n < -150) ? 0.f : (float)(s.d * p);
}

// Fused prep: weight split into stage-contiguous, bank-swizzled layout;
// tail blocks run the population encoder. Swizzle: sub-fragment s (8 u16) of
// row j stored at position s ^ ((j>>1)&3) -> wave b128 reads are 2-way max.
__global__ __launch_bounds__(256) void prep_kernel(
    const float* __restrict__ W1, const float* __restrict__ W2,
    const float* __restrict__ Wo,
    const float* __restrict__ obs, const float* __restrict__ enc_mean,
    const float* __restrict__ enc_std, u16* __restrict__ ws)
{
  int bid = blockIdx.x;
  if (bid < PREP_BLOCKS) {
    int i = bid * 256 + threadIdx.x;
    if (i < W1TOT) {                          // W1 [256][1280]
      int kc = i / 49152, r = i - kc * 49152;
      int ks = r / 24576, r2 = r - ks * 24576;
      int sel = r2 / 8192, r3 = r2 & 8191;
      int j = r3 >> 5, kkpos = r3 & 31;
      int kk = ((kkpos >> 3) ^ ((j >> 1) & 3)) * 8 + (kkpos & 7);
      ws[i] = split3(W1[j * 1280 + kc * 64 + ks * 32 + kk], sel);
    } else if (i < WOS_OFF) {                 // W2 [256][256]
      int i2 = i - W2S_OFF;
      int kc = i2 / 49152, r = i2 - kc * 49152;
      int ks = r / 24576, r2 = r - ks * 24576;
      int sel = r2 / 8192, r3 = r2 & 8191;
      int j = r3 >> 5, kkpos = r3 & 31;
      int kk = ((kkpos >> 3) ^ ((j >> 1) & 3)) * 8 + (kkpos & 7);
      ws[i] = split3(W2[j * 256 + kc * 64 + ks * 32 + kk], sel);
    } else {                                  // Wo [80][256] padded to 128 rows
      int i3 = i - WOS_OFF;
      int kc = i3 / 24576, r = i3 - kc * 24576;
      int ks = r / 12288, r2 = r - ks * 12288;
      int sel = r2 / 4096, r3 = r2 & 4095;
      int j = r3 >> 5, kkpos = r3 & 31;
      int kk = ((kkpos >> 3) ^ ((j >> 1) & 3)) * 8 + (kkpos & 7);
      float w = (j < NO) ? Wo[j * 256 + kc * 64 + ks * 32 + kk] : 0.f;
      ws[i] = split3(w, sel);
    }
    return;
  }
  // ---- encoder ----
  int gid = (bid - PREP_BLOCKS) * 256 + threadIdx.x;   // < 8192*80
  int r = gid / 80, w = gid - (gid / 80) * 80;
  const float* obsrow = obs + r * NOBS;
  u32 wbits[TT] = {0, 0, 0, 0, 0};
  #pragma unroll
  for (int e = 0; e < 16; ++e) {
    int k = w * 16 + e;
    int f = k / 10;
    float x  = obsrow[f];
    float m  = enc_mean[k];
    float sd = enc_std[k];
    float d  = __fsub_rn(x, m);
    float arg = __fdiv_rn(__fmul_rn(-0.5f, __fmul_rn(d, d)), __fmul_rn(sd, sd));
    float a = exp_cr(arg);
    float v = 0.f;
    #pragma unroll
    for (int t = 0; t < TT; ++t) {
      v = __fadd_rn(v, a);
      if (v > 0.999f) { wbits[t] |= (1u << e); v = __fsub_rn(v, 0.999f); }
    }
  }
  u16* gb = ws + GB_OFF + r * 400 + w;       // [row][t][80]
  #pragma unroll
  for (int t = 0; t < TT; ++t) gb[t * 80] = (u16)wbits[t];
}

// Async DMA of one sel-stage into LDS (nch KB chunks, 8 waves).
__device__ __forceinline__ void dma_stage(const u16* __restrict__ src, u16* dst,
                                          int nch, int wv, int lane) {
  #pragma unroll
  for (int c = 0; c < 2; ++c) {
    int ch = wv + c * 8;
    if (ch < nch)
      __builtin_amdgcn_global_load_lds((const u32*)(src + ch * 512 + lane * 8),
                                       (u32*)(dst + ch * 512), 16, 0, 0);
  }
}

// Staged GEMM, stage = one sel-plane (16KB / 8KB), double-buffered DMA, one
// barrier per stage. afr built once per (kc,ks), reused across the 3 sel
// stages. Per-column accumulation order: kc:(ks0:hi,mid,lo),(ks1:hi,mid,lo)
// == R13/R14 (bit-identical). 2 col-tiles per wave.
__device__ __forceinline__ void gemm_staged(
    const u16* lbits, int bpitch,
    const u16* __restrict__ wsbase, int nkc, int selblk, int nch,
    u16* buf0, u16* buf1, int wv, int lane, bool active, f32x4 acc[2][TT])
{
  const int m16 = lane & 15, q = lane >> 4;
  const int swz = (q ^ ((m16 >> 1) & 3)) * 8;
  const int fro0 = ((wv * 2) * 16 + m16) * 32 + swz;
  const int fro1 = fro0 + 512;
  const int sh = q * 8;
  const int nst = nkc * 6;

  dma_stage(wsbase, buf0, nch, wv, lane);
  __syncthreads();                                 // drains DMA0 (+ LDS producer)

  int st = 0;
  for (int kcks = 0; kcks < nkc * 2; ++kcks) {
    const int kc = kcks >> 1, ks = kcks & 1;
    bf16x8 afr[TT];
    #pragma unroll
    for (int t = 0; t < TT; ++t) {
      u32 bwv = *(const u32*)(lbits + (t * RR + m16) * bpitch + kc * 4 + ks * 2);
      u32 b = (bwv >> sh) & 0xFFu;
      union { u32 u[4]; bf16x8 v; } x;
      #pragma unroll
      for (int i = 0; i < 4; ++i)
        x.u[i] = ((((b >> (2 * i)) & 3u) * 0x8001u) & 0x00010001u) * 0x3F80u;
      afr[t] = x.v;
    }
    #pragma unroll
    for (int sel = 0; sel < 3; ++sel, ++st) {
      u16* cur = (st & 1) ? buf1 : buf0;
      u16* nxt = (st & 1) ? buf0 : buf1;
      if (st + 1 < nst) dma_stage(wsbase + (st + 1) * selblk, nxt, nch, wv, lane);
      if (active) {
        const bf16x8 bf0 = *(const bf16x8*)(cur + fro0);
        const bf16x8 bf1 = *(const bf16x8*)(cur + fro1);
        #pragma unroll
        for (int t = 0; t < TT; ++t)
          acc[0][t] = __builtin_amdgcn_mfma_f32_16x16x32_bf16(afr[t], bf0, acc[0][t], 0, 0, 0);
        #pragma unroll
        for (int t = 0; t < TT; ++t)
          acc[1][t] = __builtin_amdgcn_mfma_f32_16x16x32_bf16(afr[t], bf1, acc[1][t], 0, 0, 0);
      }
      __syncthreads();
    }
  }
}

// LIF recurrence over t; emit spike bits via ballot. 2 col-tiles per wave.
__device__ __forceinline__ void recur_spikes2(
    f32x4 acc[2][TT], const float* __restrict__ bias,
    int lane, int wv, u16* sbits, int spitch)
{
  const int q = lane >> 4, m16 = lane & 15;
  #pragma unroll
  for (int i = 0; i < 2; ++i) {
    int ct = wv * 2 + i;
    int j = ct * 16 + m16;
    float bj = bias[j];
    #pragma unroll
    for (int rg = 0; rg < 4; ++rg) {
      float c = 0.f, v = 0.f, sprev = 0.f;
      #pragma unroll
      for (int t = 0; t < TT; ++t) {
        float u = acc[i][t][rg];
        c = __fadd_rn(__fadd_rn(__fmul_rn(c, 0.5f), u), bj);       // (c*0.5 + u) + b
        float vd = __fmul_rn(v, 0.75f);
        v = __fadd_rn((sprev > 0.5f) ? 0.f : vd, c);               // v*0.75*(1-s) + c
        bool sp = v > 0.5f;
        u64 mask = __ballot(sp);
        if (m16 == 0) {
          int row = q * 4 + rg;
          sbits[(t * RR + row) * spitch + ct] = (u16)(mask >> (q * 16));
        }
        sprev = sp ? 1.f : 0.f;
      }
    }
  }
}

__global__ __launch_bounds__(NTHR) void snn_main(
    const float* __restrict__ b1, const float* __restrict__ b2, const float* __restrict__ bo,
    const float* __restrict__ dec_w, const float* __restrict__ dec_b, const float* __restrict__ log_std,
    const u16* __restrict__ wsW, float* __restrict__ out, int Btot)
{
  __shared__ __align__(16) u16 smem[26624];          // 53,248 B -> 2 blocks/CU
  u16* buf0 = smem;                                  // [8192] stage buffer A
  u16* buf1 = smem + 8192;                           // [8192] stage buffer B
  u16* encb = smem + 16384;                          // [5t*16r][BP1] = 7040
  u16* s1b  = smem + 23424;                          // [5t*16r][BP2] = 1600
  u16* s2b  = s1b + TT * RR * BP2;                   // 1600
  float* soacc = (float*)s1b;                        // [16][80] f32 (alias, post-L3)

  const int tid  = threadIdx.x;
  const int lane = tid & 63;
  const int wv   = tid >> 6;          // 0..7
  const int r0   = blockIdx.x * RR;

  // ---------- copy this block's spike bit-planes (16 rows x 5 t x 80 u16) ----------
  for (int it = tid; it < 800; it += NTHR) {
    const u16* gb = wsW + GB_OFF + r0 * 400;
    uint4 d = *(const uint4*)(gb + it * 8);
    int i8 = it * 8;
    int r = i8 / 400, rem = i8 - r * 400;
    int t = rem / 80, g = rem - t * 80;
    *(uint4*)(&encb[(t * RR + r) * BP1 + g]) = d;
  }
  // (visibility via gemm_staged's post-DMA barrier)

  f32x4 acc[2][TT];
  const f32x4 zero4 = {0.f, 0.f, 0.f, 0.f};
#define ZERO_ACC() { _Pragma("unroll") for (int i = 0; i < 2; ++i) \
                     _Pragma("unroll") for (int t = 0; t < TT; ++t) acc[i][t] = zero4; }

  // ---------- layer 1: [80 x 1280] @ [1280 x 256] (3-way split fused) ----------
  ZERO_ACC();
  gemm_staged(encb, BP1, wsW, 20, 8192, 16, buf0, buf1, wv, lane, true, acc);
  recur_spikes2(acc, b1, lane, wv, s1b, BP2);
  __syncthreads();

  // ---------- layer 2: [80 x 256] @ [256 x 256] ----------
  ZERO_ACC();
  gemm_staged(s1b, BP2, wsW + W2S_OFF, 4, 8192, 16, buf0, buf1, wv, lane, true, acc);
  recur_spikes2(acc, b2, lane, wv, s2b, BP2);
  __syncthreads();

  // ---------- layer 3: [80 x 256] @ [256 x 80(pad96 of 128)] — waves 0..2 ----------
  ZERO_ACC();
  gemm_staged(s2b, BP2, wsW + WOS_OFF, 4, 4096, 8, buf0, buf1, wv, lane, wv < 3, acc);
  if (wv < 3) {
    const int q = lane >> 4, m16 = lane & 15;
    #pragma unroll
    for (int i = 0; i < 2; ++i) {
      int j = (wv * 2 + i) * 16 + m16;
      bool valid = j < NO;
      float bj = valid ? bo[j] : 0.f;
      #pragma unroll
      for (int rg = 0; rg < 4; ++rg) {
        float c = 0.f, v = 0.f, sprev = 0.f;
        int cnt = 0;
        #pragma unroll
        for (int t = 0; t < TT; ++t) {
          float u = acc[i][t][rg];
          c = __fadd_rn(__fadd_rn(__fmul_rn(c, 0.5f), u), bj);
          float vd = __fmul_rn(v, 0.75f);
          v = __fadd_rn((sprev > 0.5f) ? 0.f : vd, c);
          bool sp = v > 0.5f;
          cnt += sp ? 1 : 0;
          sprev = sp ? 1.f : 0.f;
        }
        if (valid) soacc[(q * 4 + rg) * NO + j] = __fdiv_rn((float)cnt, 5.0f);
      }
    }
  }
  __syncthreads();

  // ---------- decoder: grouped dot + ELU ----------
  if (tid < RR * 8) {
    int r = tid >> 3, a = tid & 7;
    float s = 0.f;
    const float* so = soacc + r * NO + a * 10;
    #pragma unroll
    for (int p = 0; p < 10; ++p)
      s = __fadd_rn(s, __fmul_rn(so[p], dec_w[a * 10 + p]));
    s = __fadd_rn(s, dec_b[a]);
    float mu = (s > 0.f) ? s : expm1f(s);
    out[(r0 + r) * 8 + a] = mu;
  }
  if (blockIdx.x == 0 && tid < 8) {
    out[Btot * 8 + tid] = expf(log_std[tid]);
  }
}

extern "C" void kernel_launch(void* const* d_in, const int* in_sizes, int n_in,
                              void* d_out, int out_size, void* d_ws, size_t ws_size,
                              hipStream_t stream) {
  const float* obs      = (const float*)d_in[0];
  const float* enc_mean = (const float*)d_in[1];
  const float* enc_std  = (const float*)d_in[2];
  const float* W1       = (const float*)d_in[3];
  const float* b1       = (const float*)d_in[4];
  const float* W2       = (const float*)d_in[5];
  const float* b2       = (const float*)d_in[6];
  const float* Wo       = (const float*)d_in[7];
  const float* bo       = (const float*)d_in[8];
  const float* dec_w    = (const float*)d_in[9];
  const float* dec_b    = (const float*)d_in[10];
  const float* log_std  = (const float*)d_in[11];
  u16*   ws  = (u16*)d_ws;
  float* out = (float*)d_out;
  int B = in_sizes[0] / NOBS;   // 8192

  hipLaunchKernelGGL(prep_kernel, dim3(PREP_BLOCKS + ENC_BLOCKS), dim3(256), 0, stream,
                     W1, W2, Wo, obs, enc_mean, enc_std, ws);
  hipLaunchKernelGGL(snn_main, dim3(B / RR), dim3(NTHR), 0, stream,
                     b1, b2, bo, dec_w, dec_b, log_std, ws, out, B);
}

// Round 17
// 178.755 us; speedup vs baseline: 1.5611x; 1.1169x over previous
//
#include <hip/hip_runtime.h>

typedef unsigned short u16;
typedef unsigned int   u32;
typedef unsigned long long u64;
typedef __attribute__((ext_vector_type(8))) short bf16x8;
typedef __attribute__((ext_vector_type(4))) float f32x4;

#define NOBS 128
#define NN   1280
#define NH   256
#define NO   80
#define TT   5
#define RR   16          // batch rows per block
#define NTHR 512         // 8 waves/block, 2 col-tiles per wave
#define BP1  88          // layer1 bits LDS pitch (u16)
#define BP2  20          // layer2/3 bits pitch (u16)

// ws layout (u16 units), stage-contiguous: [kc][ks][sel][rows][32], rows
// XOR-swizzled within (see prep). W1s [20][2][3][256][32] @0 ;
// W2s [4][2][3][256][32] @983040 ; Wos [4][2][3][128][32] @1179648 (pad128)
// gbits [8192 rows][5 t][80] @1277952
#define W1TOT   983040
#define W2S_OFF 983040
#define WOS_OFF 1179648
#define WS_TOTAL 1277952
#define GB_OFF  WS_TOTAL

#define PREP_BLOCKS 4992          // WS_TOTAL/256
#define ENC_BLOCKS  2560          // 8192*80/256

#define VMW2()  asm volatile("s_waitcnt vmcnt(2)" ::: "memory")
#define VMW0()  asm volatile("s_waitcnt vmcnt(0)" ::: "memory")
#define FENCE() asm volatile("" ::: "memory")

__device__ __forceinline__ float bf2f(u16 u) {
  union { u32 i; float f; } x; x.i = ((u32)u) << 16; return x.f;
}
__device__ __forceinline__ u16 f2bf(float f) {
  union { float f; u32 i; } x; x.f = f;
  u32 i = x.i + 0x7FFFu + ((x.i >> 16) & 1u);   // RNE
  return (u16)(i >> 16);
}

// 3-way bf16 split: w ~= hi + mid + lo, residual <= 2^-27 |w|.
__device__ __forceinline__ u16 split3(float w, int sel) {
  u16 hi = f2bf(w);
  if (sel == 0) return hi;
  float r1 = __fsub_rn(w, bf2f(hi));        // exact
  u16 mid = f2bf(r1);
  if (sel == 1) return mid;
  float r2 = __fsub_rn(r1, bf2f(mid));      // exact
  return f2bf(r2);
}

// Inline near-correctly-rounded f32 exp via f64 degree-11 Taylor.
__device__ __forceinline__ float exp_cr(float arg) {
  double xa = (double)arg;
  double nd = __builtin_rint(xa * 1.4426950408889634074);
  double r  = fma(nd, -6.93147180369123816490e-01, xa);
  r         = fma(nd, -1.90821492927058770002e-10, r);
  double p = 2.50521083854417187751e-08;
  p = fma(p, r, 2.75573192239858906526e-07);
  p = fma(p, r, 2.75573192239858906526e-06);
  p = fma(p, r, 2.48015873015873015873e-05);
  p = fma(p, r, 1.98412698412698412698e-04);
  p = fma(p, r, 1.38888888888888888889e-03);
  p = fma(p, r, 8.33333333333333333333e-03);
  p = fma(p, r, 4.16666666666666666667e-02);
  p = fma(p, r, 1.66666666666666666667e-01);
  p = fma(p, r, 0.5);
  p = fma(p, r, 1.0);
  p = fma(p, r, 1.0);
  int n = (int)nd;
  union { u64 u; double d; } s;
  s.u = ((u64)(u32)(n + 1023)) << 52;
  return (n < -150) ? 0.f : (float)(s.d * p);
}

// Fused prep: weight split into stage-contiguous, bank-swizzled layout;
// tail blocks run the population encoder. Swizzle: sub-fragment s (8 u16) of
// row j stored at position s ^ ((j>>1)&3) -> wave b128 reads are 2-way max.
__global__ __launch_bounds__(256) void prep_kernel(
    const float* __restrict__ W1, const float* __restrict__ W2,
    const float* __restrict__ Wo,
    const float* __restrict__ obs, const float* __restrict__ enc_mean,
    const float* __restrict__ enc_std, u16* __restrict__ ws)
{
  int bid = blockIdx.x;
  if (bid < PREP_BLOCKS) {
    int i = bid * 256 + threadIdx.x;
    if (i < W1TOT) {                          // W1 [256][1280]
      int kc = i / 49152, r = i - kc * 49152;
      int ks = r / 24576, r2 = r - ks * 24576;
      int sel = r2 / 8192, r3 = r2 & 8191;
      int j = r3 >> 5, kkpos = r3 & 31;
      int kk = ((kkpos >> 3) ^ ((j >> 1) & 3)) * 8 + (kkpos & 7);
      ws[i] = split3(W1[j * 1280 + kc * 64 + ks * 32 + kk], sel);
    } else if (i < WOS_OFF) {                 // W2 [256][256]
      int i2 = i - W2S_OFF;
      int kc = i2 / 49152, r = i2 - kc * 49152;
      int ks = r / 24576, r2 = r - ks * 24576;
      int sel = r2 / 8192, r3 = r2 & 8191;
      int j = r3 >> 5, kkpos = r3 & 31;
      int kk = ((kkpos >> 3) ^ ((j >> 1) & 3)) * 8 + (kkpos & 7);
      ws[i] = split3(W2[j * 256 + kc * 64 + ks * 32 + kk], sel);
    } else {                                  // Wo [80][256] padded to 128 rows
      int i3 = i - WOS_OFF;
      int kc = i3 / 24576, r = i3 - kc * 24576;
      int ks = r / 12288, r2 = r - ks * 12288;
      int sel = r2 / 4096, r3 = r2 & 4095;
      int j = r3 >> 5, kkpos = r3 & 31;
      int kk = ((kkpos >> 3) ^ ((j >> 1) & 3)) * 8 + (kkpos & 7);
      float w = (j < NO) ? Wo[j * 256 + kc * 64 + ks * 32 + kk] : 0.f;
      ws[i] = split3(w, sel);
    }
    return;
  }
  // ---- encoder ----
  int gid = (bid - PREP_BLOCKS) * 256 + threadIdx.x;   // < 8192*80
  int r = gid / 80, w = gid - (gid / 80) * 80;
  const float* obsrow = obs + r * NOBS;
  u32 wbits[TT] = {0, 0, 0, 0, 0};
  #pragma unroll
  for (int e = 0; e < 16; ++e) {
    int k = w * 16 + e;
    int f = k / 10;
    float x  = obsrow[f];
    float m  = enc_mean[k];
    float sd = enc_std[k];
    float d  = __fsub_rn(x, m);
    float arg = __fdiv_rn(__fmul_rn(-0.5f, __fmul_rn(d, d)), __fmul_rn(sd, sd));
    float a = exp_cr(arg);
    float v = 0.f;
    #pragma unroll
    for (int t = 0; t < TT; ++t) {
      v = __fadd_rn(v, a);
      if (v > 0.999f) { wbits[t] |= (1u << e); v = __fsub_rn(v, 0.999f); }
    }
  }
  u16* gb = ws + GB_OFF + r * 400 + w;       // [row][t][80]
  #pragma unroll
  for (int t = 0; t < TT; ++t) gb[t * 80] = (u16)wbits[t];
}

// DMA this wave's 2KB stage slice (1024 u16) into LDS: 2 instructions,
// wave-uniform LDS base + implicit lane*16.
__device__ __forceinline__ void dma2(const u16* __restrict__ src, u16* dst, int lane) {
  __builtin_amdgcn_global_load_lds((const u32*)(src + lane * 8), (u32*)dst, 16, 0, 0);
  __builtin_amdgcn_global_load_lds((const u32*)(src + 512 + lane * 8),
                                   (u32*)(dst + 512), 16, 0, 0);
}

// Barrier-free wave-private staged GEMM: each wave DMAs only the 32 B-rows it
// reads (2KB/stage) into its own triple-buffered LDS slice; pacing is per-wave
// s_waitcnt vmcnt(2) (one full stage of slack). FINAL stage waits vmcnt(0) —
// its own DMAs are the only ones left in flight (R16's race: vmcnt(2) was
// already satisfied and read unlanded data). 6 stages per kcks, 3 bufs ->
// buffer index == sel. Per-column accumulation order
// kc:(ks0:hi,mid,lo),(ks1:hi,mid,lo) — bit-identical to R13/R14/R15.
__device__ __forceinline__ void gemm_wp(
    const u16* lbits, int bpitch,
    const u16* __restrict__ wsbase, int nkc, int selblk,
    u16* mybuf,                     // this wave's [3][1024] u16 slices
    int wv, int lane, f32x4 acc[2][TT])
{
  const int m16 = lane & 15, q = lane >> 4;
  const int swz = (q ^ ((m16 >> 1) & 3)) * 8;
  const int lro0 = m16 * 32 + swz;           // local row m16
  const int lro1 = lro0 + 512;               // local row m16+16
  const int sh = q * 8;
  const int nst = nkc * 6;
  const u16* slice = wsbase + wv * 1024;

  dma2(slice, mybuf, lane);                  // st 0 -> buf 0
  dma2(slice + selblk, mybuf + 1024, lane);  // st 1 -> buf 1
  FENCE();

  int st = 0;
  for (int kcks = 0; kcks < nkc * 2; ++kcks) {
    const int kc = kcks >> 1, ks = kcks & 1;
    bf16x8 afr[TT];
    #pragma unroll
    for (int t = 0; t < TT; ++t) {
      u32 bwv = *(const u32*)(lbits + (t * RR + m16) * bpitch + kc * 4 + ks * 2);
      u32 b = (bwv >> sh) & 0xFFu;
      union { u32 u[4]; bf16x8 v; } x;
      #pragma unroll
      for (int i = 0; i < 4; ++i)
        x.u[i] = ((((b >> (2 * i)) & 3u) * 0x8001u) & 0x00010001u) * 0x3F80u;
      afr[t] = x.v;
    }
    #pragma unroll
    for (int sel = 0; sel < 3; ++sel, ++st) {
      u16* cur = mybuf + sel * 1024;         // st % 3 == sel (6 stages/kcks)
      if (st + 1 < nst) { VMW2(); } else { VMW0(); }   // last stage: own DMAs are the tail
      const bf16x8 bf0 = *(const bf16x8*)(cur + lro0);
      const bf16x8 bf1 = *(const bf16x8*)(cur + lro1);
      #pragma unroll
      for (int t = 0; t < TT; ++t)
        acc[0][t] = __builtin_amdgcn_mfma_f32_16x16x32_bf16(afr[t], bf0, acc[0][t], 0, 0, 0);
      #pragma unroll
      for (int t = 0; t < TT; ++t)
        acc[1][t] = __builtin_amdgcn_mfma_f32_16x16x32_bf16(afr[t], bf1, acc[1][t], 0, 0, 0);
      FENCE();
      if (st + 2 < nst)                      // st+2 -> buf (sel+2)%3 (consumed)
        dma2(slice + (st + 2) * selblk, mybuf + ((sel + 2) % 3) * 1024, lane);
      FENCE();
    }
  }
}

// LIF recurrence over t; emit spike bits via ballot. 2 col-tiles per wave.
__device__ __forceinline__ void recur_spikes2(
    f32x4 acc[2][TT], const float* __restrict__ bias,
    int lane, int wv, u16* sbits, int spitch)
{
  const int q = lane >> 4, m16 = lane & 15;
  #pragma unroll
  for (int i = 0; i < 2; ++i) {
    int ct = wv * 2 + i;
    int j = ct * 16 + m16;
    float bj = bias[j];
    #pragma unroll
    for (int rg = 0; rg < 4; ++rg) {
      float c = 0.f, v = 0.f, sprev = 0.f;
      #pragma unroll
      for (int t = 0; t < TT; ++t) {
        float u = acc[i][t][rg];
        c = __fadd_rn(__fadd_rn(__fmul_rn(c, 0.5f), u), bj);       // (c*0.5 + u) + b
        float vd = __fmul_rn(v, 0.75f);
        v = __fadd_rn((sprev > 0.5f) ? 0.f : vd, c);               // v*0.75*(1-s) + c
        bool sp = v > 0.5f;
        u64 mask = __ballot(sp);
        if (m16 == 0) {
          int row = q * 4 + rg;
          sbits[(t * RR + row) * spitch + ct] = (u16)(mask >> (q * 16));
        }
        sprev = sp ? 1.f : 0.f;
      }
    }
  }
}

__global__ __launch_bounds__(NTHR) void snn_main(
    const float* __restrict__ b1, const float* __restrict__ b2, const float* __restrict__ bo,
    const float* __restrict__ dec_w, const float* __restrict__ dec_b, const float* __restrict__ log_std,
    const u16* __restrict__ wsW, float* __restrict__ out, int Btot)
{
  __shared__ __align__(16) u16 smem[37376];          // 74,752 B -> 2 blocks/CU
  u16* bufs = smem;                                  // [8 waves][3][1024]
  u16* encb = smem + 24576;                          // [5t*16r][BP1] = 7040
  u16* s1b  = encb + 7040;                           // [5t*16r][BP2] = 1600
  u16* s2b  = s1b + 1600;                            // 1600
  float* soacc = (float*)(s2b + 1600);               // [16][80] f32 (own region)

  const int tid  = threadIdx.x;
  const int lane = tid & 63;
  const int wv   = tid >> 6;          // 0..7
  const int r0   = blockIdx.x * RR;
  u16* mybuf = bufs + wv * 3072;

  // ---------- copy this block's spike bit-planes (16 rows x 5 t x 80 u16) ----------
  for (int it = tid; it < 800; it += NTHR) {
    const u16* gb = wsW + GB_OFF + r0 * 400;
    uint4 d = *(const uint4*)(gb + it * 8);
    int i8 = it * 8;
    int r = i8 / 400, rem = i8 - r * 400;
    int t = rem / 80, g = rem - t * 80;
    *(uint4*)(&encb[(t * RR + r) * BP1 + g]) = d;
  }
  __syncthreads();

  f32x4 acc[2][TT];
  const f32x4 zero4 = {0.f, 0.f, 0.f, 0.f};
#define ZERO_ACC() { _Pragma("unroll") for (int i = 0; i < 2; ++i) \
                     _Pragma("unroll") for (int t = 0; t < TT; ++t) acc[i][t] = zero4; }

  // ---------- layer 1: [80 x 1280] @ [1280 x 256] (3-way split fused) ----------
  ZERO_ACC();
  gemm_wp(encb, BP1, wsW, 20, 8192, mybuf, wv, lane, acc);
  recur_spikes2(acc, b1, lane, wv, s1b, BP2);
  __syncthreads();

  // ---------- layer 2: [80 x 256] @ [256 x 256] ----------
  ZERO_ACC();
  gemm_wp(s1b, BP2, wsW + W2S_OFF, 4, 8192, mybuf, wv, lane, acc);
  recur_spikes2(acc, b2, lane, wv, s2b, BP2);
  __syncthreads();

  // ---------- layer 3: [80 x 256] @ [256 x 80(pad96 of 128)] — waves 0..2 ----------
  if (wv < 3) {
    ZERO_ACC();
    gemm_wp(s2b, BP2, wsW + WOS_OFF, 4, 4096, mybuf, wv, lane, acc);
    const int q = lane >> 4, m16 = lane & 15;
    #pragma unroll
    for (int i = 0; i < 2; ++i) {
      int j = (wv * 2 + i) * 16 + m16;
      bool valid = j < NO;
      float bj = valid ? bo[j] : 0.f;
      #pragma unroll
      for (int rg = 0; rg < 4; ++rg) {
        float c = 0.f, v = 0.f, sprev = 0.f;
        int cnt = 0;
        #pragma unroll
        for (int t = 0; t < TT; ++t) {
          float u = acc[i][t][rg];
          c = __fadd_rn(__fadd_rn(__fmul_rn(c, 0.5f), u), bj);
          float vd = __fmul_rn(v, 0.75f);
          v = __fadd_rn((sprev > 0.5f) ? 0.f : vd, c);
          bool sp = v > 0.5f;
          cnt += sp ? 1 : 0;
          sprev = sp ? 1.f : 0.f;
        }
        if (valid) soacc[(q * 4 + rg) * NO + j] = __fdiv_rn((float)cnt, 5.0f);
      }
    }
  }
  __syncthreads();

  // ---------- decoder: grouped dot + ELU ----------
  if (tid < RR * 8) {
    int r = tid >> 3, a = tid & 7;
    float s = 0.f;
    const float* so = soacc + r * NO + a * 10;
    #pragma unroll
    for (int p = 0; p < 10; ++p)
      s = __fadd_rn(s, __fmul_rn(so[p], dec_w[a * 10 + p]));
    s = __fadd_rn(s, dec_b[a]);
    float mu = (s > 0.f) ? s : expm1f(s);
    out[(r0 + r) * 8 + a] = mu;
  }
  if (blockIdx.x == 0 && tid < 8) {
    out[Btot * 8 + tid] = expf(log_std[tid]);
  }
}

extern "C" void kernel_launch(void* const* d_in, const int* in_sizes, int n_in,
                              void* d_out, int out_size, void* d_ws, size_t ws_size,
                              hipStream_t stream) {
  const float* obs      = (const float*)d_in[0];
  const float* enc_mean = (const float*)d_in[1];
  const float* enc_std  = (const float*)d_in[2];
  const float* W1       = (const float*)d_in[3];
  const float* b1       = (const float*)d_in[4];
  const float* W2       = (const float*)d_in[5];
  const float* b2       = (const float*)d_in[6];
  const float* Wo       = (const float*)d_in[7];
  const float* bo       = (const float*)d_in[8];
  const float* dec_w    = (const float*)d_in[9];
  const float* dec_b    = (const float*)d_in[10];
  const float* log_std  = (const float*)d_in[11];
  u16*   ws  = (u16*)d_ws;
  float* out = (float*)d_out;
  int B = in_sizes[0] / NOBS;   // 8192

  hipLaunchKernelGGL(prep_kernel, dim3(PREP_BLOCKS + ENC_BLOCKS), dim3(256), 0, stream,
                     W1, W2, Wo, obs, enc_mean, enc_std, ws);
  hipLaunchKernelGGL(snn_main, dim3(B / RR), dim3(NTHR), 0, stream,
                     b1, b2, bo, dec_w, dec_b, log_std, ws, out, B);
}